// Round 4
// baseline (208.465 us; speedup 1.0000x reference)
//
#include <hip/hip_runtime.h>
#include <math.h>

#define BN    32
#define CN    256
#define HN    56
#define WN    56
#define HWN   (HN * WN)          // 3136
#define CHWN  (CN * HWN)         // 802816
#define NPOS  (BN * HWN)         // 100352
#define KCH   8                  // channel chunks
#define CPK   (CN / KCH)         // 32 channels per chunk
#define NP4   (NPOS / 4)         // 25088 fx4 positions
#define P4BLK (NP4 / 256)        // 98 blocks per chunk slice

typedef float fx4 __attribute__((ext_vector_type(4)));

// K1: partial channel reduction, fx4 over positions. Thread = (chunk k, 4 pos),
// reduces 32 channels with fully unrolled independent 16B loads.
// 784 blocks; each wave-load is 64 lanes x 16B = 1KB contiguous.
__global__ __launch_bounds__(256) void sa_reduce_part(const float* __restrict__ x,
                                                      fx4* __restrict__ psum,
                                                      fx4* __restrict__ pmax) {
    int k  = blockIdx.x / P4BLK;                 // 0..7
    int pb = blockIdx.x - k * P4BLK;
    int p4 = pb * 256 + threadIdx.x;             // 0..NP4-1
    int e  = p4 * 4;                             // element position
    int b  = e / HWN;                            // HWN divisible by 4: no b-crossing
    int s  = e - b * HWN;
    const fx4* xp = (const fx4*)(x + (size_t)b * CHWN + (size_t)(k * CPK) * HWN + s);
    fx4 sum = {0.f, 0.f, 0.f, 0.f};
    fx4 m = {-INFINITY, -INFINITY, -INFINITY, -INFINITY};
#pragma unroll
    for (int c = 0; c < CPK; ++c) {
        fx4 v = xp[c * (HWN / 4)];
        sum += v;
        m.x = fmaxf(m.x, v.x);
        m.y = fmaxf(m.y, v.y);
        m.z = fmaxf(m.z, v.z);
        m.w = fmaxf(m.w, v.w);
    }
    psum[(size_t)k * NP4 + p4] = sum;
    pmax[(size_t)k * NP4 + p4] = m;
}

// K2: fold the 8 partials into avg/max maps (fx4).
__global__ __launch_bounds__(256) void sa_combine(const fx4* __restrict__ psum,
                                                  const fx4* __restrict__ pmax,
                                                  fx4* __restrict__ avg,
                                                  fx4* __restrict__ mx) {
    int p4 = blockIdx.x * 256 + threadIdx.x;
    fx4 sum = psum[p4];
    fx4 m = pmax[p4];
#pragma unroll
    for (int k = 1; k < KCH; ++k) {
        fx4 s2 = psum[(size_t)k * NP4 + p4];
        fx4 m2 = pmax[(size_t)k * NP4 + p4];
        sum += s2;
        m.x = fmaxf(m.x, m2.x);
        m.y = fmaxf(m.y, m2.y);
        m.z = fmaxf(m.z, m2.z);
        m.w = fmaxf(m.w, m2.w);
    }
    avg[p4] = sum * (1.0f / (float)CN);
    mx[p4] = m;
}

// K3: 7x7 conv over the 2-channel (avg,max) map + sigmoid -> att map.
// Inputs 0.8 MB -> L2-resident; compute trivial.
__global__ __launch_bounds__(256) void sa_conv(const float* __restrict__ avg,
                                               const float* __restrict__ mx,
                                               const float* __restrict__ cw,
                                               float* __restrict__ att) {
    int p = blockIdx.x * 256 + threadIdx.x;
    if (p >= NPOS) return;
    int b = p / HWN;
    int s = p - b * HWN;
    int h = s / WN;
    int w = s - h * WN;
    const float* a0 = avg + b * HWN;
    const float* m0 = mx + b * HWN;
    float acc = 0.0f;
#pragma unroll
    for (int kh = 0; kh < 7; ++kh) {
        int hh = h + kh - 3;
        if (hh < 0 || hh >= HN) continue;
#pragma unroll
        for (int kw = 0; kw < 7; ++kw) {
            int ww = w + kw - 3;
            if (ww < 0 || ww >= WN) continue;
            int idx = hh * WN + ww;
            acc = fmaf(cw[kh * 7 + kw],      a0[idx], acc);
            acc = fmaf(cw[49 + kh * 7 + kw], m0[idx], acc);
        }
    }
    att[p] = 1.0f / (1.0f + expf(-acc));
}

// K4: out = x * att (broadcast over channels), fx4 + nontemporal store.
__global__ __launch_bounds__(256) void sa_mul(const fx4* __restrict__ x4,
                                              const float* __restrict__ att,
                                              fx4* __restrict__ out4) {
    int b = blockIdx.y;
    int i = blockIdx.x * 256 + threadIdx.x;          // fx4 idx within b-plane
    int s = (i * 4) % HWN;                           // spatial pos (mult of 4)
    const fx4 a = *(const fx4*)(att + b * HWN + s);
    size_t gi = (size_t)b * (CHWN / 4) + i;
    fx4 v = x4[gi];
    v *= a;
    __builtin_nontemporal_store(v, &out4[gi]);
}

extern "C" void kernel_launch(void* const* d_in, const int* in_sizes, int n_in,
                              void* d_out, int out_size, void* d_ws, size_t ws_size,
                              hipStream_t stream) {
    const float* x  = (const float*)d_in[0];
    const float* cw = (const float*)d_in[1];
    float* out = (float*)d_out;

    fx4* psum = (fx4*)d_ws;                 // KCH*NP4 fx4
    fx4* pmax = psum + (size_t)KCH * NP4;   // KCH*NP4 fx4
    fx4* avg  = pmax + (size_t)KCH * NP4;   // NP4 fx4
    fx4* mx   = avg + NP4;                  // NP4 fx4
    float* att = (float*)(mx + NP4);        // NPOS floats

    sa_reduce_part<<<KCH * P4BLK, 256, 0, stream>>>(x, psum, pmax);
    sa_combine<<<P4BLK, 256, 0, stream>>>(psum, pmax, avg, mx);
    sa_conv<<<NPOS / 256, 256, 0, stream>>>((const float*)avg, (const float*)mx, cw, att);

    dim3 mgrid(CHWN / 4 / 256, BN);         // (784, 32)
    sa_mul<<<mgrid, 256, 0, stream>>>((const fx4*)x, att, (fx4*)out);
}

// Round 5
// 206.742 us; speedup vs baseline: 1.0083x; 1.0083x over previous
//
#include <hip/hip_runtime.h>
#include <math.h>

#define BN    32
#define CN    256
#define HN    56
#define WN    56
#define HWN   (HN * WN)          // 3136
#define CHWN  (CN * HWN)         // 802816
#define NPOS  (BN * HWN)         // 100352
#define KCH   8                  // channel chunks for split-K reduce
#define CPK   (CN / KCH)         // 32 channels per chunk
#define NP4   (NPOS / 4)         // 25088 fx4 positions
#define P4BLK (NP4 / 256)        // 98 blocks per chunk slice

// Fused kernel tiling
#define RT_ROWS  14              // rows per tile -> 4 tiles/plane
#define TILE_POS (RT_ROWS * WN)  // 784
#define TILE_F4  (TILE_POS / 4)  // 196
#define HALO_ROWS (RT_ROWS + 6)  // 20 (±3 conv halo)
#define LDSW     62              // 56 + 2*3 zero-pad columns
#define CQ       4               // channel quarters -> 64 ch per block
#define CPQ      (CN / CQ)       // 64

typedef float fx4 __attribute__((ext_vector_type(4)));

// K1: split-K partial channel reduction, fx4 over positions.
// 784 blocks (12 waves/CU); each thread: 32 fully-unrolled independent 16B loads.
__global__ __launch_bounds__(256) void sa_reduce_part(const float* __restrict__ x,
                                                      fx4* __restrict__ psum,
                                                      fx4* __restrict__ pmax) {
    int k  = blockIdx.x / P4BLK;                 // 0..7
    int pb = blockIdx.x - k * P4BLK;
    int p4 = pb * 256 + threadIdx.x;             // 0..NP4-1
    int e  = p4 * 4;
    int b  = e / HWN;                            // HWN % 4 == 0: no b-crossing
    int s  = e - b * HWN;
    const fx4* xp = (const fx4*)(x + (size_t)b * CHWN + (size_t)(k * CPK) * HWN + s);
    fx4 sum = {0.f, 0.f, 0.f, 0.f};
    fx4 m = {-INFINITY, -INFINITY, -INFINITY, -INFINITY};
#pragma unroll
    for (int c = 0; c < CPK; ++c) {
        fx4 v = xp[c * (HWN / 4)];
        sum += v;
        m.x = fmaxf(m.x, v.x);
        m.y = fmaxf(m.y, v.y);
        m.z = fmaxf(m.z, v.z);
        m.w = fmaxf(m.w, v.w);
    }
    psum[(size_t)k * NP4 + p4] = sum;
    pmax[(size_t)k * NP4 + p4] = m;
}

// K2: fused combine + 7x7 conv + sigmoid + broadcast multiply.
// Block = (channel-quarter cq, row-tile rt, batch b). Grid (4,4,32) = 512 blocks.
__global__ __launch_bounds__(256) void sa_fused(const float* __restrict__ x,
                                                const fx4* __restrict__ psum,
                                                const fx4* __restrict__ pmax,
                                                const float* __restrict__ cw,
                                                float* __restrict__ out) {
    __shared__ float lavg[HALO_ROWS * LDSW];
    __shared__ float lmax[HALO_ROWS * LDSW];
    __shared__ float latt[TILE_POS];

    const int t  = threadIdx.x;
    const int cq = blockIdx.x;       // 0..3
    const int rt = blockIdx.y;       // 0..3
    const int b  = blockIdx.z;       // 0..31
    const int r0 = rt * RT_ROWS;     // first tile row

    // Phase 0: zero the padded planes (2 * 20 * 62 = 2480 floats).
    for (int i = t; i < HALO_ROWS * LDSW; i += 256) {
        lavg[i] = 0.0f;
        lmax[i] = 0.0f;
    }
    __syncthreads();

    // Phase A: fold 8 split-K partials for tile + halo rows into LDS interior.
    // Halo fx4 cells: 20 rows x 14 fx4/row = 280.
    for (int i = t; i < HALO_ROWS * (WN / 4); i += 256) {
        int lr   = i / (WN / 4);           // 0..19
        int col4 = i - lr * (WN / 4);      // 0..13
        int gr   = r0 - 3 + lr;            // global row
        if (gr < 0 || gr >= HN) continue;  // stays zero
        int p4 = b * (HWN / 4) + gr * (WN / 4) + col4;
        fx4 sum = psum[p4];
        fx4 m = pmax[p4];
#pragma unroll
        for (int k = 1; k < KCH; ++k) {
            fx4 s2 = psum[(size_t)k * NP4 + p4];
            fx4 m2 = pmax[(size_t)k * NP4 + p4];
            sum += s2;
            m.x = fmaxf(m.x, m2.x);
            m.y = fmaxf(m.y, m2.y);
            m.z = fmaxf(m.z, m2.z);
            m.w = fmaxf(m.w, m2.w);
        }
        sum *= (1.0f / (float)CN);
        int o = lr * LDSW + 3 + col4 * 4;  // interior starts at col 3
        lavg[o + 0] = sum.x; lavg[o + 1] = sum.y; lavg[o + 2] = sum.z; lavg[o + 3] = sum.w;
        lmax[o + 0] = m.x;   lmax[o + 1] = m.y;   lmax[o + 2] = m.z;   lmax[o + 3] = m.w;
    }
    __syncthreads();

    // Phase B: 7x7 conv + sigmoid over the 784 tile positions.
    for (int j = t; j < TILE_POS; j += 256) {
        int h = j / WN;                    // local row 0..13
        int w = j - h * WN;                // col 0..55
        float acc = 0.0f;
#pragma unroll
        for (int kh = 0; kh < 7; ++kh) {
#pragma unroll
            for (int kw = 0; kw < 7; ++kw) {
                // lds row h+kh (row 0 = global r0-3), lds col w+kw (interior at +3)
                acc = fmaf(cw[kh * 7 + kw],      lavg[(h + kh) * LDSW + w + kw], acc);
                acc = fmaf(cw[49 + kh * 7 + kw], lmax[(h + kh) * LDSW + w + kw], acc);
            }
        }
        latt[j] = 1.0f / (1.0f + expf(-acc));
    }
    __syncthreads();

    // Phase C: out = x * att for this tile's 64 channels.
    // 64 ch * 196 fx4 = 12544 = 49 * 256 -> full utilization.
    const size_t planebase = (size_t)b * (CHWN / 4);  // fx4 units
    const int tilebase = r0 * (WN / 4);               // fx4 offset within plane
    const fx4* x4 = (const fx4*)x;
    fx4* out4 = (fx4*)out;
#pragma unroll 7
    for (int it = 0; it < 49; ++it) {
        int q = it * 256 + t;
        int c = q / TILE_F4;               // 0..63
        int s4 = q - c * TILE_F4;          // 0..195
        size_t gi = planebase + (size_t)(cq * CPQ + c) * (HWN / 4) + tilebase + s4;
        fx4 a = *(const fx4*)(latt + s4 * 4);
        fx4 v = x4[gi];
        v *= a;
        __builtin_nontemporal_store(v, &out4[gi]);
    }
}

extern "C" void kernel_launch(void* const* d_in, const int* in_sizes, int n_in,
                              void* d_out, int out_size, void* d_ws, size_t ws_size,
                              hipStream_t stream) {
    const float* x  = (const float*)d_in[0];
    const float* cw = (const float*)d_in[1];
    float* out = (float*)d_out;

    fx4* psum = (fx4*)d_ws;                 // KCH*NP4 fx4
    fx4* pmax = psum + (size_t)KCH * NP4;   // KCH*NP4 fx4

    sa_reduce_part<<<KCH * P4BLK, 256, 0, stream>>>(x, psum, pmax);

    dim3 fgrid(CQ, HN / RT_ROWS, BN);       // (4, 4, 32)
    sa_fused<<<fgrid, 256, 0, stream>>>(x, psum, pmax, cw, out);
}